// Round 7
// baseline (314.207 us; speedup 1.0000x reference)
//
#include <hip/hip_runtime.h>
#include <hip/hip_bf16.h>
#include <stdint.h>

#define B_ 32
#define N_ 1024
#define H_ 256

typedef short bf16x8 __attribute__((ext_vector_type(8)));
typedef float floatx4 __attribute__((ext_vector_type(4)));

__device__ inline unsigned short f2bs(float x) {
    __hip_bfloat16 h = __float2bfloat16(x);
    return __builtin_bit_cast(unsigned short, h);
}

// ---------------------------------------------------------------------------
// Kernel A: u vectors. u[0]=W_i@a1, u[1]=W_c@a1, u[2]=W_i@a2, u[3]=W_c@a2.
// ---------------------------------------------------------------------------
__global__ __launch_bounds__(256)
void k_uvec(const float* __restrict__ Wi, const float* __restrict__ Wc,
            const float* __restrict__ a, float* __restrict__ U) {
    int k = blockIdx.x;
    int t = threadIdx.x;
    float wi = Wi[k * H_ + t];
    float wc = Wc[k * H_ + t];
    float a1 = a[t], a2 = a[H_ + t];
    float p0 = wi * a1, p1 = wc * a1, p2 = wi * a2, p3 = wc * a2;
    for (int off = 32; off; off >>= 1) {
        p0 += __shfl_xor(p0, off);
        p1 += __shfl_xor(p1, off);
        p2 += __shfl_xor(p2, off);
        p3 += __shfl_xor(p3, off);
    }
    __shared__ float red[4][4];
    int w = t >> 6;
    if ((t & 63) == 0) { red[w][0] = p0; red[w][1] = p1; red[w][2] = p2; red[w][3] = p3; }
    __syncthreads();
    if (t == 0) {
        U[0 * H_ + k] = red[0][0] + red[1][0] + red[2][0] + red[3][0];
        U[1 * H_ + k] = red[0][1] + red[1][1] + red[2][1] + red[3][1];
        U[2 * H_ + k] = red[0][2] + red[1][2] + red[2][2] + red[3][2];
        U[3 * H_ + k] = red[0][3] + red[1][3] + red[2][3] + red[3][3];
    }
}

// ---------------------------------------------------------------------------
// Kernel P: W -> fragment-ordered bf16 WtF (B-operand layout for k_gemm).
// ---------------------------------------------------------------------------
__global__ __launch_bounds__(256)
void k_prep(const float* __restrict__ Wi, const float* __restrict__ Wc,
            unsigned short* __restrict__ WtFi, unsigned short* __restrict__ WtFc) {
    __shared__ float tile[64][65];   // [k_local][n_local]
    int mat = blockIdx.x >> 4;
    int tr = ((blockIdx.x >> 2) & 3) * 64;  // k-tile origin
    int tc = (blockIdx.x & 3) * 64;         // n-tile origin
    const float* W = mat ? Wc : Wi;
    unsigned short* WtF = mat ? WtFc : WtFi;
    int t = threadIdx.x;
    int rr = t >> 2, c4 = (t & 3) * 16;
    const float* src = W + (size_t)(tr + rr) * H_ + tc + c4;
#pragma unroll
    for (int j = 0; j < 4; ++j) {
        float4 v = *reinterpret_cast<const float4*>(src + j * 4);
        tile[rr][c4 + 4 * j + 0] = v.x;
        tile[rr][c4 + 4 * j + 1] = v.y;
        tile[rr][c4 + 4 * j + 2] = v.z;
        tile[rr][c4 + 4 * j + 3] = v.w;
    }
    __syncthreads();
#pragma unroll
    for (int h = 0; h < 2; ++h) {
        int s = h * 256 + t;
        int ksl = s >> 8;
        int cl  = (s >> 6) & 3;
        int ll  = s & 63;
        int m16v = ll & 15, quadv = ll >> 4;
        int nloc = cl * 16 + m16v;
        int kb = ksl * 32 + quadv * 8;
        unsigned int pk[4];
#pragma unroll
        for (int jj = 0; jj < 4; ++jj) {
            unsigned short lo = f2bs(tile[kb + 2 * jj][nloc]);
            unsigned short hi = f2bs(tile[kb + 2 * jj + 1][nloc]);
            pk[jj] = (unsigned int)lo | ((unsigned int)hi << 16);
        }
        int ksg = (tr >> 5) + ksl;
        int cg  = (tc >> 4) + cl;
        *reinterpret_cast<uint4*>(WtF + ((size_t)(ksg * 16 + cg) * 64 + ll) * 8) =
            *reinterpret_cast<uint4*>(pk);
    }
}

// ---------------------------------------------------------------------------
// Kernel C: fused. Wh = inp @ W_sel(row) via MFMA (fragment-ordered output
// WhF), plus Wh1/Wh2 score dots (fp32, u-vector trick) in the same K-loop.
// ---------------------------------------------------------------------------
__global__ __launch_bounds__(256)
void k_gemm(const float* __restrict__ inp, const int* __restrict__ l,
            const unsigned short* __restrict__ WtFi, const unsigned short* __restrict__ WtFc,
            unsigned short* __restrict__ WhF, const float* __restrict__ U,
            float* __restrict__ Wh1, float* __restrict__ Wh2) {
    __shared__ unsigned short bbuf[2][4096];  // 8 KB per buffer
    int blk = blockIdx.x;
    int b  = blk >> 5;
    int r0 = ((blk >> 1) & 15) * 64;
    int n0 = (blk & 1) * 128;
    int t = threadIdx.x;
    int w = t >> 6;
    int lane = t & 63;
    int quad = lane >> 4, m16 = lane & 15;
    int rowb = r0 + w * 16;

    int l0 = l[2 * b], l1 = l[2 * b + 1];
    bool allI = (l0 <= r0) && (r0 + 64 <= l1);
    bool allC = (l1 <= r0) || (l0 >= r0 + 64);
    int npass = (allI || allC) ? 1 : 2;

    int row = rowb + m16;
    bool sel = (row >= l0) && (row < l1);
    const float* xrow = inp + ((size_t)(b * N_ + row)) * H_;
    const float* u1 = U + (sel ? 0 : H_);
    const float* u2 = U + 2 * H_ + (sel ? 0 : H_);
    bool doWh = (n0 == 0);
    float d1 = 0.f, d2 = 0.f;

    unsigned short* fb = WhF + (size_t)b * (N_ * H_);
    int cb = n0 >> 4;   // 0 or 8

    int j0 = rowb + quad * 4;
    int ksO = j0 >> 5;
    int laneF = m16 + 16 * ((j0 & 31) >> 3);
    int jj0 = j0 & 7;

    for (int pass = 0; pass < npass; ++pass) {
        const unsigned short* WtF =
            (npass == 1) ? (allI ? WtFi : WtFc) : (pass == 0 ? WtFi : WtFc);
        const unsigned short* gbase = WtF + cb * 512;

        floatx4 acc[8];
#pragma unroll
        for (int c = 0; c < 8; ++c) acc[c] = (floatx4){0.f, 0.f, 0.f, 0.f};

        {   // prologue: stage ks=0 into buf0 (linear 8 KB copy)
            uint4 v0 = *reinterpret_cast<const uint4*>(gbase + (size_t)t * 8);
            uint4 v1 = *reinterpret_cast<const uint4*>(gbase + (size_t)(256 + t) * 8);
            *reinterpret_cast<uint4*>(&bbuf[0][t * 8]) = v0;
            *reinterpret_cast<uint4*>(&bbuf[0][(256 + t) * 8]) = v1;
        }
        for (int ks = 0; ks < 8; ++ks) {
            __syncthreads();
            uint4 v0, v1;
            if (ks < 7) {
                v0 = *reinterpret_cast<const uint4*>(gbase + (size_t)(ks + 1) * 8192 + t * 8);
                v1 = *reinterpret_cast<const uint4*>(gbase + (size_t)(ks + 1) * 8192 + (256 + t) * 8);
            }
            const float4 xa = *reinterpret_cast<const float4*>(xrow + ks * 32 + quad * 8);
            const float4 xb = *reinterpret_cast<const float4*>(xrow + ks * 32 + quad * 8 + 4);
            if (pass == 0 && doWh) {
                const float4 ua = *reinterpret_cast<const float4*>(u1 + ks * 32 + quad * 8);
                const float4 ub = *reinterpret_cast<const float4*>(u1 + ks * 32 + quad * 8 + 4);
                const float4 va = *reinterpret_cast<const float4*>(u2 + ks * 32 + quad * 8);
                const float4 vb = *reinterpret_cast<const float4*>(u2 + ks * 32 + quad * 8 + 4);
                d1 += xa.x * ua.x + xa.y * ua.y + xa.z * ua.z + xa.w * ua.w
                    + xb.x * ub.x + xb.y * ub.y + xb.z * ub.z + xb.w * ub.w;
                d2 += xa.x * va.x + xa.y * va.y + xa.z * va.z + xa.w * va.w
                    + xb.x * vb.x + xb.y * vb.y + xb.z * vb.z + xb.w * vb.w;
            }
            unsigned int pk0 = (unsigned int)f2bs(xa.x) | ((unsigned int)f2bs(xa.y) << 16);
            unsigned int pk1 = (unsigned int)f2bs(xa.z) | ((unsigned int)f2bs(xa.w) << 16);
            unsigned int pk2 = (unsigned int)f2bs(xb.x) | ((unsigned int)f2bs(xb.y) << 16);
            unsigned int pk3 = (unsigned int)f2bs(xb.z) | ((unsigned int)f2bs(xb.w) << 16);
            uint4 apk = {pk0, pk1, pk2, pk3};
            bf16x8 af = __builtin_bit_cast(bf16x8, apk);

            const unsigned short* bptr = &bbuf[ks & 1][lane * 8];
#pragma unroll
            for (int c = 0; c < 8; ++c) {
                bf16x8 bfr = *reinterpret_cast<const bf16x8*>(bptr + c * 512);
                acc[c] = __builtin_amdgcn_mfma_f32_16x16x32_bf16(af, bfr, acc[c], 0, 0, 0);
            }
            if (ks < 7) {
                *reinterpret_cast<uint4*>(&bbuf[(ks + 1) & 1][t * 8]) = v0;
                *reinterpret_cast<uint4*>(&bbuf[(ks + 1) & 1][(256 + t) * 8]) = v1;
            }
        }
        __syncthreads();

#pragma unroll
        for (int c = 0; c < 8; ++c) {
            size_t base = ((size_t)((ksO * 16 + cb + c) * 64) + laneF) * 8 + jj0;
            if (npass == 1) {
                unsigned int lo = (unsigned int)f2bs(acc[c][0]) | ((unsigned int)f2bs(acc[c][1]) << 16);
                unsigned int hi = (unsigned int)f2bs(acc[c][2]) | ((unsigned int)f2bs(acc[c][3]) << 16);
                uint2 v = {lo, hi};
                *reinterpret_cast<uint2*>(fb + base) = v;
            } else {
                bool want[4]; bool all = true, none = true;
#pragma unroll
                for (int r = 0; r < 4; ++r) {
                    int j = j0 + r;
                    bool s2 = (j >= l0) && (j < l1);
                    want[r] = (pass == 0) ? s2 : !s2;
                    all = all && want[r]; none = none && !want[r];
                }
                if (all) {
                    unsigned int lo = (unsigned int)f2bs(acc[c][0]) | ((unsigned int)f2bs(acc[c][1]) << 16);
                    unsigned int hi = (unsigned int)f2bs(acc[c][2]) | ((unsigned int)f2bs(acc[c][3]) << 16);
                    uint2 v = {lo, hi};
                    *reinterpret_cast<uint2*>(fb + base) = v;
                } else if (!none) {
#pragma unroll
                    for (int r = 0; r < 4; ++r)
                        if (want[r]) fb[base + r] = f2bs(acc[c][r]);
                }
            }
        }
    }

    if (doWh) {
        d1 += __shfl_xor(d1, 16); d1 += __shfl_xor(d1, 32);
        d2 += __shfl_xor(d2, 16); d2 += __shfl_xor(d2, 32);
        if (quad == 0) {
            Wh1[b * N_ + rowb + m16] = d1;
            Wh2[b * N_ + rowb + m16] = d2;
        }
    }
}

// ---------------------------------------------------------------------------
// Kernel D: fully register-resident masked-softmax + P@Wh MFMA + elu.
// NO LDS, NO BARRIERS. Each lane computes exactly the 8 score elements its
// MFMA A-fragment needs (lane(m16,quad) -> row i=rowtile+m16, cols
// j=ks*32+quad*8+jj): two dwordx4 A-loads per ks cover 16 full cache lines.
// Wave = 16 rows x 128 cols (c-half); block = 2 row-tiles x 2 c-halves.
// Row sums on the matrix pipe (ones B-fragment). No max-subtraction
// (shift-invariant, scores bounded ~|12| -- validated rounds 6).
// Grid = B*(N/32) = 1024, XCD-swizzled. 4 waves/SIMD via launch_bounds.
// ---------------------------------------------------------------------------
__global__ __launch_bounds__(256, 4)
void k_attn(const float* __restrict__ A, const float* __restrict__ Wh1,
            const float* __restrict__ Wh2, const unsigned short* __restrict__ WhF,
            float* __restrict__ out) {
    int t = threadIdx.x, w = t >> 6, lane = t & 63;
    int quad = lane >> 4, m16 = lane & 15;
    int bi = blockIdx.x;
    int b = (bi & 7) * 4 + (bi >> 8);        // XCD-swizzle: 4 batches per XCD
    int tile = (bi >> 3) & 31;
    int rowtile = tile * 32 + (w & 1) * 16;  // this wave's 16-row tile
    int ch = w >> 1;                         // c-half: cols [ch*128, ch*128+128)
    int i = rowtile + m16;                   // this lane's score row

    float wh1 = Wh1[b * N_ + i];
    const float* arow = A + ((size_t)(b * N_ + i)) * N_;
    const float* w2b  = Wh2 + b * N_;
    const unsigned short* WB = WhF + (size_t)b * (N_ * H_) + (size_t)(ch * 8) * 512;

    unsigned short oneb = f2bs(1.0f);
    bf16x8 bones = {(short)oneb, (short)oneb, (short)oneb, (short)oneb,
                    (short)oneb, (short)oneb, (short)oneb, (short)oneb};
    floatx4 acc[8], rsum = (floatx4){0.f, 0.f, 0.f, 0.f};
#pragma unroll
    for (int cc = 0; cc < 8; ++cc) acc[cc] = (floatx4){0.f, 0.f, 0.f, 0.f};

#pragma unroll 2
    for (int ks = 0; ks < 32; ++ks) {
        int j0 = ks * 32 + quad * 8;
        float4 a0 = *reinterpret_cast<const float4*>(arow + j0);
        float4 a1 = *reinterpret_cast<const float4*>(arow + j0 + 4);
        float4 u0 = *reinterpret_cast<const float4*>(w2b + j0);
        float4 u1 = *reinterpret_cast<const float4*>(w2b + j0 + 4);
        float aa[8] = {a0.x, a0.y, a0.z, a0.w, a1.x, a1.y, a1.z, a1.w};
        float uu[8] = {u0.x, u0.y, u0.z, u0.w, u1.x, u1.y, u1.z, u1.w};
        unsigned int pk[4];
#pragma unroll
        for (int h2 = 0; h2 < 4; ++h2) {
            float p2[2];
#pragma unroll
            for (int g = 0; g < 2; ++g) {
                int jj = h2 * 2 + g;
                float a_ = aa[jj] + ((j0 + jj) == i ? 1.0f : 0.0f);  // A + I
                float e  = (wh1 + uu[jj]) * a_;
                float lv = fmaxf(e, 0.2f * e);                       // leaky_relu
                p2[g] = a_ > 0.f ? __expf(lv) : 0.f;
            }
            pk[h2] = (unsigned int)f2bs(p2[0]) | ((unsigned int)f2bs(p2[1]) << 16);
        }
        uint4 apk = {pk[0], pk[1], pk[2], pk[3]};
        bf16x8 af = __builtin_bit_cast(bf16x8, apk);

        rsum = __builtin_amdgcn_mfma_f32_16x16x32_bf16(af, bones, rsum, 0, 0, 0);
        const unsigned short* bks = WB + (size_t)(ks * 16) * 512 + lane * 8;
#pragma unroll
        for (int cc = 0; cc < 8; ++cc) {
            bf16x8 bfv = *reinterpret_cast<const bf16x8*>(bks + cc * 512);
            acc[cc] = __builtin_amdgcn_mfma_f32_16x16x32_bf16(af, bfv, acc[cc], 0, 0, 0);
        }
    }

    // Epilogue: normalize, elu, store. C/D: col=m16, row=quad*4+r.
    float inv[4];
#pragma unroll
    for (int r = 0; r < 4; ++r) inv[r] = 1.0f / rsum[r];
#pragma unroll
    for (int cc = 0; cc < 8; ++cc) {
        int col = (ch * 8 + cc) * 16 + m16;
#pragma unroll
        for (int r = 0; r < 4; ++r) {
            int m = quad * 4 + r;
            float v = acc[cc][r] * inv[r];
            v = v > 0.f ? v : __expf(v) - 1.0f;
            out[((size_t)(b * N_ + rowtile + m)) * H_ + col] = v;
        }
    }
}

// ---------------------------------------------------------------------------
extern "C" void kernel_launch(void* const* d_in, const int* in_sizes, int n_in,
                              void* d_out, int out_size, void* d_ws, size_t ws_size,
                              hipStream_t stream) {
    const float* inp = (const float*)d_in[0];
    const float* A   = (const float*)d_in[1];
    const int*   l   = (const int*)d_in[2];
    const float* Wi  = (const float*)d_in[3];
    const float* Wc  = (const float*)d_in[4];
    const float* a   = (const float*)d_in[5];
    float* out = (float*)d_out;

    char* ws = (char*)d_ws;
    size_t off = 0;
    unsigned short* WhF  = (unsigned short*)(ws + off); off += (size_t)B_ * N_ * H_ * 2;
    float* Wh1 = (float*)(ws + off); off += (size_t)B_ * N_ * 4;
    float* Wh2 = (float*)(ws + off); off += (size_t)B_ * N_ * 4;
    float* U   = (float*)(ws + off); off += 4 * H_ * 4;
    unsigned short* WtFi = (unsigned short*)(ws + off); off += (size_t)H_ * H_ * 2;
    unsigned short* WtFc = (unsigned short*)(ws + off); off += (size_t)H_ * H_ * 2;

    k_uvec<<<H_, 256, 0, stream>>>(Wi, Wc, a, U);
    k_prep<<<32, 256, 0, stream>>>(Wi, Wc, WtFi, WtFc);
    k_gemm<<<B_ * 16 * 2, 256, 0, stream>>>(inp, l, WtFi, WtFc, WhF, U, Wh1, Wh2);
    k_attn<<<B_ * (N_ / 32), 256, 0, stream>>>(A, Wh1, Wh2, WhF, out);
}

// Round 8
// 287.267 us; speedup vs baseline: 1.0938x; 1.0938x over previous
//
#include <hip/hip_runtime.h>
#include <hip/hip_bf16.h>
#include <stdint.h>

#define B_ 32
#define N_ 1024
#define H_ 256
#define PF_PITCH 520   // shorts per ks row: 1040 B -> +4 bank rotation per ks

typedef short bf16x8 __attribute__((ext_vector_type(8)));
typedef float floatx4 __attribute__((ext_vector_type(4)));

__device__ inline unsigned short f2bs(float x) {
    __hip_bfloat16 h = __float2bfloat16(x);
    return __builtin_bit_cast(unsigned short, h);
}

// ---------------------------------------------------------------------------
// Kernel PRE: blocks [0,32) = W -> fragment-ordered bf16 WtF;
//             blocks [32,288) = u-vector dots (one output k per block).
// ---------------------------------------------------------------------------
__global__ __launch_bounds__(256)
void k_pre(const float* __restrict__ Wi, const float* __restrict__ Wc,
           const float* __restrict__ a,
           unsigned short* __restrict__ WtFi, unsigned short* __restrict__ WtFc,
           float* __restrict__ U) {
    int t = threadIdx.x;
    if (blockIdx.x >= 32) {
        // ---- u vectors ----
        int k = blockIdx.x - 32;
        float wi = Wi[k * H_ + t];
        float wc = Wc[k * H_ + t];
        float a1 = a[t], a2 = a[H_ + t];
        float p0 = wi * a1, p1 = wc * a1, p2 = wi * a2, p3 = wc * a2;
        for (int off = 32; off; off >>= 1) {
            p0 += __shfl_xor(p0, off);
            p1 += __shfl_xor(p1, off);
            p2 += __shfl_xor(p2, off);
            p3 += __shfl_xor(p3, off);
        }
        __shared__ float red[4][4];
        int w = t >> 6;
        if ((t & 63) == 0) { red[w][0] = p0; red[w][1] = p1; red[w][2] = p2; red[w][3] = p3; }
        __syncthreads();
        if (t == 0) {
            U[0 * H_ + k] = red[0][0] + red[1][0] + red[2][0] + red[3][0];
            U[1 * H_ + k] = red[0][1] + red[1][1] + red[2][1] + red[3][1];
            U[2 * H_ + k] = red[0][2] + red[1][2] + red[2][2] + red[3][2];
            U[3 * H_ + k] = red[0][3] + red[1][3] + red[2][3] + red[3][3];
        }
        return;
    }
    // ---- W transpose/convert to fragment order ----
    __shared__ float tile[64][65];   // [k_local][n_local]
    int mat = blockIdx.x >> 4;
    int tr = ((blockIdx.x >> 2) & 3) * 64;  // k-tile origin
    int tc = (blockIdx.x & 3) * 64;         // n-tile origin
    const float* W = mat ? Wc : Wi;
    unsigned short* WtF = mat ? WtFc : WtFi;
    int rr = t >> 2, c4 = (t & 3) * 16;
    const float* src = W + (size_t)(tr + rr) * H_ + tc + c4;
#pragma unroll
    for (int j = 0; j < 4; ++j) {
        float4 v = *reinterpret_cast<const float4*>(src + j * 4);
        tile[rr][c4 + 4 * j + 0] = v.x;
        tile[rr][c4 + 4 * j + 1] = v.y;
        tile[rr][c4 + 4 * j + 2] = v.z;
        tile[rr][c4 + 4 * j + 3] = v.w;
    }
    __syncthreads();
#pragma unroll
    for (int h = 0; h < 2; ++h) {
        int s = h * 256 + t;
        int ksl = s >> 8;
        int cl  = (s >> 6) & 3;
        int ll  = s & 63;
        int m16v = ll & 15, quadv = ll >> 4;
        int nloc = cl * 16 + m16v;
        int kb = ksl * 32 + quadv * 8;
        unsigned int pk[4];
#pragma unroll
        for (int jj = 0; jj < 4; ++jj) {
            unsigned short lo = f2bs(tile[kb + 2 * jj][nloc]);
            unsigned short hi = f2bs(tile[kb + 2 * jj + 1][nloc]);
            pk[jj] = (unsigned int)lo | ((unsigned int)hi << 16);
        }
        int ksg = (tr >> 5) + ksl;
        int cg  = (tc >> 4) + cl;
        *reinterpret_cast<uint4*>(WtF + ((size_t)(ksg * 16 + cg) * 64 + ll) * 8) =
            *reinterpret_cast<uint4*>(pk);
    }
}

// ---------------------------------------------------------------------------
// Kernel C: fused. Wh = inp @ W_sel(row) via MFMA (fragment-ordered output
// WhF), plus Wh1/Wh2 score dots (fp32, u-vector trick) in the same K-loop.
// ---------------------------------------------------------------------------
__global__ __launch_bounds__(256)
void k_gemm(const float* __restrict__ inp, const int* __restrict__ l,
            const unsigned short* __restrict__ WtFi, const unsigned short* __restrict__ WtFc,
            unsigned short* __restrict__ WhF, const float* __restrict__ U,
            float* __restrict__ Wh1, float* __restrict__ Wh2) {
    __shared__ unsigned short bbuf[2][4096];  // 8 KB per buffer
    int blk = blockIdx.x;
    int b  = blk >> 5;
    int r0 = ((blk >> 1) & 15) * 64;
    int n0 = (blk & 1) * 128;
    int t = threadIdx.x;
    int w = t >> 6;
    int lane = t & 63;
    int quad = lane >> 4, m16 = lane & 15;
    int rowb = r0 + w * 16;

    int l0 = l[2 * b], l1 = l[2 * b + 1];
    bool allI = (l0 <= r0) && (r0 + 64 <= l1);
    bool allC = (l1 <= r0) || (l0 >= r0 + 64);
    int npass = (allI || allC) ? 1 : 2;

    int row = rowb + m16;
    bool sel = (row >= l0) && (row < l1);
    const float* xrow = inp + ((size_t)(b * N_ + row)) * H_;
    const float* u1 = U + (sel ? 0 : H_);
    const float* u2 = U + 2 * H_ + (sel ? 0 : H_);
    bool doWh = (n0 == 0);
    float d1 = 0.f, d2 = 0.f;

    unsigned short* fb = WhF + (size_t)b * (N_ * H_);
    int cb = n0 >> 4;   // 0 or 8

    int j0 = rowb + quad * 4;
    int ksO = j0 >> 5;
    int laneF = m16 + 16 * ((j0 & 31) >> 3);
    int jj0 = j0 & 7;

    for (int pass = 0; pass < npass; ++pass) {
        const unsigned short* WtF =
            (npass == 1) ? (allI ? WtFi : WtFc) : (pass == 0 ? WtFi : WtFc);
        const unsigned short* gbase = WtF + cb * 512;

        floatx4 acc[8];
#pragma unroll
        for (int c = 0; c < 8; ++c) acc[c] = (floatx4){0.f, 0.f, 0.f, 0.f};

        {   // prologue: stage ks=0 into buf0 (linear 8 KB copy)
            uint4 v0 = *reinterpret_cast<const uint4*>(gbase + (size_t)t * 8);
            uint4 v1 = *reinterpret_cast<const uint4*>(gbase + (size_t)(256 + t) * 8);
            *reinterpret_cast<uint4*>(&bbuf[0][t * 8]) = v0;
            *reinterpret_cast<uint4*>(&bbuf[0][(256 + t) * 8]) = v1;
        }
        for (int ks = 0; ks < 8; ++ks) {
            __syncthreads();
            uint4 v0, v1;
            if (ks < 7) {
                v0 = *reinterpret_cast<const uint4*>(gbase + (size_t)(ks + 1) * 8192 + t * 8);
                v1 = *reinterpret_cast<const uint4*>(gbase + (size_t)(ks + 1) * 8192 + (256 + t) * 8);
            }
            const float4 xa = *reinterpret_cast<const float4*>(xrow + ks * 32 + quad * 8);
            const float4 xb = *reinterpret_cast<const float4*>(xrow + ks * 32 + quad * 8 + 4);
            if (pass == 0 && doWh) {
                const float4 ua = *reinterpret_cast<const float4*>(u1 + ks * 32 + quad * 8);
                const float4 ub = *reinterpret_cast<const float4*>(u1 + ks * 32 + quad * 8 + 4);
                const float4 va = *reinterpret_cast<const float4*>(u2 + ks * 32 + quad * 8);
                const float4 vb = *reinterpret_cast<const float4*>(u2 + ks * 32 + quad * 8 + 4);
                d1 += xa.x * ua.x + xa.y * ua.y + xa.z * ua.z + xa.w * ua.w
                    + xb.x * ub.x + xb.y * ub.y + xb.z * ub.z + xb.w * ub.w;
                d2 += xa.x * va.x + xa.y * va.y + xa.z * va.z + xa.w * va.w
                    + xb.x * vb.x + xb.y * vb.y + xb.z * vb.z + xb.w * vb.w;
            }
            unsigned int pk0 = (unsigned int)f2bs(xa.x) | ((unsigned int)f2bs(xa.y) << 16);
            unsigned int pk1 = (unsigned int)f2bs(xa.z) | ((unsigned int)f2bs(xa.w) << 16);
            unsigned int pk2 = (unsigned int)f2bs(xb.x) | ((unsigned int)f2bs(xb.y) << 16);
            unsigned int pk3 = (unsigned int)f2bs(xb.z) | ((unsigned int)f2bs(xb.w) << 16);
            uint4 apk = {pk0, pk1, pk2, pk3};
            bf16x8 af = __builtin_bit_cast(bf16x8, apk);

            const unsigned short* bptr = &bbuf[ks & 1][lane * 8];
#pragma unroll
            for (int c = 0; c < 8; ++c) {
                bf16x8 bfr = *reinterpret_cast<const bf16x8*>(bptr + c * 512);
                acc[c] = __builtin_amdgcn_mfma_f32_16x16x32_bf16(af, bfr, acc[c], 0, 0, 0);
            }
            if (ks < 7) {
                *reinterpret_cast<uint4*>(&bbuf[(ks + 1) & 1][t * 8]) = v0;
                *reinterpret_cast<uint4*>(&bbuf[(ks + 1) & 1][(256 + t) * 8]) = v1;
            }
        }
        __syncthreads();

#pragma unroll
        for (int c = 0; c < 8; ++c) {
            size_t base = ((size_t)((ksO * 16 + cb + c) * 64) + laneF) * 8 + jj0;
            if (npass == 1) {
                unsigned int lo = (unsigned int)f2bs(acc[c][0]) | ((unsigned int)f2bs(acc[c][1]) << 16);
                unsigned int hi = (unsigned int)f2bs(acc[c][2]) | ((unsigned int)f2bs(acc[c][3]) << 16);
                uint2 v = {lo, hi};
                *reinterpret_cast<uint2*>(fb + base) = v;
            } else {
                bool want[4]; bool all = true, none = true;
#pragma unroll
                for (int r = 0; r < 4; ++r) {
                    int j = j0 + r;
                    bool s2 = (j >= l0) && (j < l1);
                    want[r] = (pass == 0) ? s2 : !s2;
                    all = all && want[r]; none = none && !want[r];
                }
                if (all) {
                    unsigned int lo = (unsigned int)f2bs(acc[c][0]) | ((unsigned int)f2bs(acc[c][1]) << 16);
                    unsigned int hi = (unsigned int)f2bs(acc[c][2]) | ((unsigned int)f2bs(acc[c][3]) << 16);
                    uint2 v = {lo, hi};
                    *reinterpret_cast<uint2*>(fb + base) = v;
                } else if (!none) {
#pragma unroll
                    for (int r = 0; r < 4; ++r)
                        if (want[r]) fb[base + r] = f2bs(acc[c][r]);
                }
            }
        }
    }

    if (doWh) {
        d1 += __shfl_xor(d1, 16); d1 += __shfl_xor(d1, 32);
        d2 += __shfl_xor(d2, 16); d2 += __shfl_xor(d2, 32);
        if (quad == 0) {
            Wh1[b * N_ + rowb + m16] = d1;
            Wh2[b * N_ + rowb + m16] = d2;
        }
    }
}

// ---------------------------------------------------------------------------
// Kernel D: fused masked-softmax + P@Wh (MFMA) + elu. M=16 rows per block.
// Round-6 structure (best measured: phase-split, no reductions, swizzled
// conflict-free pfrag, MFMA row sums) but ONE 16-row tile per block:
// LDS 33.3 KB -> 4 blocks/CU (vs 2 at M=32). Scores computed exactly once.
// Grid = B*(N/16) = 2048, XCD-swizzled (4 batches per XCD -> 2 MB WhF/XCD L2).
// ---------------------------------------------------------------------------
__global__ __launch_bounds__(256, 4)
void k_attn(const float* __restrict__ A, const float* __restrict__ Wh1,
            const float* __restrict__ Wh2, const unsigned short* __restrict__ WhF,
            float* __restrict__ out) {
    __shared__ unsigned short pfrag[32 * PF_PITCH];  // 33,280 B
    int t = threadIdx.x, w = t >> 6, lane = t & 63;
    int quad = lane >> 4, m16 = lane & 15;
    int bi = blockIdx.x;
    int b = (bi & 7) * 4 + ((bi >> 3) >> 6);   // XCD-swizzle: 4 batches per XCD
    int tile = (bi >> 3) & 63;
    int rowbase = tile * 16;

    const float* Wh2b = Wh2 + b * N_;
    float4 w2v[4];
#pragma unroll
    for (int ch = 0; ch < 4; ++ch)
        w2v[ch] = *reinterpret_cast<const float4*>(Wh2b + ch * 256 + lane * 4);

    int ksl = lane >> 3;
    int q2 = (lane & 7) >> 1;
    int jj0 = (lane & 1) * 4;

    // Phase 1: scores -> exp -> bf16 pack -> swizzled A-fragment LDS.
#pragma unroll
    for (int q = 0; q < 4; ++q) {
        int m = w * 4 + q;                 // row within 16-tile
        int i = rowbase + m;
        float wh1 = Wh1[b * N_ + i];
        const float* Arow = A + ((size_t)(b * N_ + i)) * N_;
        int s = m + 16 * q2;
        int sw = s ^ ((s >> 3) & 7);
        int sls = sw * 8 + jj0;
#pragma unroll
        for (int ch = 0; ch < 4; ++ch) {
            float4 av = *reinterpret_cast<const float4*>(Arow + ch * 256 + lane * 4);
            if ((i >> 2) == (ch * 64 + lane)) ((float*)&av)[i & 3] += 1.0f;  // A + I
            float aa[4] = {av.x, av.y, av.z, av.w};
            float ww[4] = {w2v[ch].x, w2v[ch].y, w2v[ch].z, w2v[ch].w};
            float p[4];
#pragma unroll
            for (int c = 0; c < 4; ++c) {
                float e  = (wh1 + ww[c]) * aa[c];
                float lv = fmaxf(e, 0.2f * e);          // leaky_relu
                p[c] = aa[c] > 0.f ? __expf(lv) : 0.f;  // no max-subtraction
            }
            unsigned int lo = (unsigned int)f2bs(p[0]) | ((unsigned int)f2bs(p[1]) << 16);
            unsigned int hi = (unsigned int)f2bs(p[2]) | ((unsigned int)f2bs(p[3]) << 16);
            uint2 v = {lo, hi};
            int ks = ch * 8 + ksl;
            *reinterpret_cast<uint2*>(pfrag + ks * PF_PITCH + sls) = v;
        }
    }
    __syncthreads();

    // Phase 2: P[16 x 1024] @ Wh[1024 x 256] + ones-column row sums.
    const unsigned short* WB = WhF + (size_t)b * (N_ * H_);
    int rs = (lane ^ ((lane >> 3) & 7)) * 8;   // swizzled read offset (shorts)
    unsigned short oneb = f2bs(1.0f);
    bf16x8 bones = {(short)oneb, (short)oneb, (short)oneb, (short)oneb,
                    (short)oneb, (short)oneb, (short)oneb, (short)oneb};
    floatx4 acc[4], rsum = (floatx4){0.f, 0.f, 0.f, 0.f};
#pragma unroll
    for (int cc = 0; cc < 4; ++cc) acc[cc] = (floatx4){0.f, 0.f, 0.f, 0.f};
#pragma unroll 4
    for (int ks = 0; ks < 32; ++ks) {
        bf16x8 af = *reinterpret_cast<const bf16x8*>(pfrag + ks * PF_PITCH + rs);
        rsum = __builtin_amdgcn_mfma_f32_16x16x32_bf16(af, bones, rsum, 0, 0, 0);
#pragma unroll
        for (int cc = 0; cc < 4; ++cc) {
            int c = w * 4 + cc;
            bf16x8 bfv = *reinterpret_cast<const bf16x8*>(
                WB + ((size_t)((ks * 16 + c) * 64 + lane)) * 8);
            acc[cc] = __builtin_amdgcn_mfma_f32_16x16x32_bf16(af, bfv, acc[cc], 0, 0, 0);
        }
    }

    // Epilogue: normalize, elu, store. C/D: col=m16, row=quad*4+r.
    float inv[4];
#pragma unroll
    for (int r = 0; r < 4; ++r) inv[r] = 1.0f / rsum[r];
#pragma unroll
    for (int cc = 0; cc < 4; ++cc) {
        int col = (w * 4 + cc) * 16 + m16;
#pragma unroll
        for (int r = 0; r < 4; ++r) {
            int m = quad * 4 + r;
            float v = acc[cc][r] * inv[r];
            v = v > 0.f ? v : __expf(v) - 1.0f;
            out[((size_t)(b * N_ + rowbase + m)) * H_ + col] = v;
        }
    }
}

// ---------------------------------------------------------------------------
extern "C" void kernel_launch(void* const* d_in, const int* in_sizes, int n_in,
                              void* d_out, int out_size, void* d_ws, size_t ws_size,
                              hipStream_t stream) {
    const float* inp = (const float*)d_in[0];
    const float* A   = (const float*)d_in[1];
    const int*   l   = (const int*)d_in[2];
    const float* Wi  = (const float*)d_in[3];
    const float* Wc  = (const float*)d_in[4];
    const float* a   = (const float*)d_in[5];
    float* out = (float*)d_out;

    char* ws = (char*)d_ws;
    size_t off = 0;
    unsigned short* WhF  = (unsigned short*)(ws + off); off += (size_t)B_ * N_ * H_ * 2;
    float* Wh1 = (float*)(ws + off); off += (size_t)B_ * N_ * 4;
    float* Wh2 = (float*)(ws + off); off += (size_t)B_ * N_ * 4;
    float* U   = (float*)(ws + off); off += 4 * H_ * 4;
    unsigned short* WtFi = (unsigned short*)(ws + off); off += (size_t)H_ * H_ * 2;
    unsigned short* WtFc = (unsigned short*)(ws + off); off += (size_t)H_ * H_ * 2;

    k_pre<<<288, 256, 0, stream>>>(Wi, Wc, a, WtFi, WtFc, U);
    k_gemm<<<B_ * 16 * 2, 256, 0, stream>>>(inp, l, WtFi, WtFc, WhF, U, Wh1, Wh2);
    k_attn<<<B_ * (N_ / 16), 256, 0, stream>>>(A, Wh1, Wh2, WhF, out);
}